// Round 21
// baseline (592.641 us; speedup 1.0000x reference)
//
#include <hip/hip_runtime.h>

#define TT 512   // sequence length
#define BB 64    // batch
#define HH 128   // hidden
#define G4 512   // 4*H
#define PF 4     // prefetch ring depth (even, divides TT)

typedef float f32x4  __attribute__((ext_vector_type(4)));
typedef _Float16 f16x4v __attribute__((ext_vector_type(4)));
typedef _Float16 f16x8v __attribute__((ext_vector_type(8)));

// barrier that waits ONLY on LDS (lgkmcnt) -- global loads/stores stay in flight
__device__ __forceinline__ void barrier_lds_only() {
    asm volatile("s_waitcnt lgkmcnt(0)\n\ts_barrier" ::: "memory");
}

// ---------------- merged fp32 -> fp16 convert: 5 segments, 1 launch ----------------
__global__ __launch_bounds__(256) void convert_all(
    const float4* __restrict__ s0, f16x4v* __restrict__ d0, int n0,
    const float4* __restrict__ s1, f16x4v* __restrict__ d1, int n1,
    const float4* __restrict__ s2, f16x4v* __restrict__ d2, int n2,
    const float4* __restrict__ s3, f16x4v* __restrict__ d3, int n3,
    const float4* __restrict__ s4, f16x4v* __restrict__ d4, int n4)
{
    const int tid0 = blockIdx.x * 256 + threadIdx.x;
    const int strd = gridDim.x * 256;
    #define CVT(S, D, N)                                            \
        for (int i = tid0; i < (N); i += strd) {                    \
            float4 f = (S)[i];                                      \
            f16x4v h;                                               \
            h[0] = (_Float16)f.x; h[1] = (_Float16)f.y;             \
            h[2] = (_Float16)f.z; h[3] = (_Float16)f.w;             \
            (D)[i] = h;                                             \
        }
    CVT(s0, d0, n0)
    CVT(s1, d1, n1)
    CVT(s2, d2, n2)
    CVT(s3, d3, n3)
    CVT(s4, d4, n4)
    #undef CVT
}

// ---------------- f16 pre-GEMM, fwd+bwd fused via blockIdx.z (R20-proven) ----------
template<int K>
__global__ __launch_bounds__(256) void gemm_f16z(
    const _Float16* __restrict__ Af,
    const _Float16* __restrict__ Wf0, const _Float16* __restrict__ Wf1,
    const float* __restrict__ b0f, const float* __restrict__ b1f,
    const float* __restrict__ b0r, const float* __restrict__ b1r,
    _Float16* __restrict__ C0, _Float16* __restrict__ C1)
{
    const int z = blockIdx.z;
    const _Float16* __restrict__ Wf = z ? Wf1 : Wf0;
    const float* __restrict__ b0 = z ? b0r : b0f;
    const float* __restrict__ b1 = z ? b1r : b1f;
    _Float16* __restrict__ C = z ? C1 : C0;

    constexpr int NC  = K / 32;
    constexpr int LDA = 40;                  // f16 per staged row (32 + 8 pad)
    __shared__ _Float16 As[128 * LDA];
    __shared__ _Float16 Ws[128 * LDA];

    const int bm  = blockIdx.x * 128;
    const int bn  = blockIdx.y * 128;
    const int tid = threadIdx.x;
    const int wv  = tid >> 6;
    const int l   = tid & 63;
    const int jl  = l & 15;
    const int rg  = l >> 4;
    const int wr  = wv >> 1;
    const int wc  = wv & 1;

    const int sr = tid >> 1;
    const int sc = (tid & 1) * 16;

    const _Float16* Ap = Af + (size_t)(bm + sr) * K + sc;
    const _Float16* Wp = Wf + (size_t)(bn + sr) * K + sc;

    f32x4 acc[4][4];
    #pragma unroll
    for (int i = 0; i < 4; ++i)
        #pragma unroll
        for (int j = 0; j < 4; ++j)
            acc[i][j] = (f32x4){0.f, 0.f, 0.f, 0.f};

    f16x8v pa[2], pw[2];
    pa[0] = *(const f16x8v*)(Ap);     pa[1] = *(const f16x8v*)(Ap + 8);
    pw[0] = *(const f16x8v*)(Wp);     pw[1] = *(const f16x8v*)(Wp + 8);

    #pragma unroll 1
    for (int c = 0; c < NC; ++c) {
        __syncthreads();
        {
            int off = sr * LDA + sc;
            *(f16x8v*)&As[off]     = pa[0];
            *(f16x8v*)&As[off + 8] = pa[1];
            *(f16x8v*)&Ws[off]     = pw[0];
            *(f16x8v*)&Ws[off + 8] = pw[1];
        }
        __syncthreads();
        if (c + 1 < NC) {
            pa[0] = *(const f16x8v*)(Ap + (c + 1) * 32);
            pa[1] = *(const f16x8v*)(Ap + (c + 1) * 32 + 8);
            pw[0] = *(const f16x8v*)(Wp + (c + 1) * 32);
            pw[1] = *(const f16x8v*)(Wp + (c + 1) * 32 + 8);
        }
        f16x8v ah[4], wh[4];
        #pragma unroll
        for (int t = 0; t < 4; ++t) {
            ah[t] = *(const f16x8v*)&As[(wr * 64 + t * 16 + jl) * LDA + rg * 8];
            wh[t] = *(const f16x8v*)&Ws[(wc * 64 + t * 16 + jl) * LDA + rg * 8];
        }
        #pragma unroll
        for (int tm = 0; tm < 4; ++tm)
            #pragma unroll
            for (int tn = 0; tn < 4; ++tn)
                acc[tm][tn] = __builtin_amdgcn_mfma_f32_16x16x32_f16(
                    ah[tm], wh[tn], acc[tm][tn], 0, 0, 0);
    }

    // epilogue: C layout col=lane&15 (n), row=(lane>>4)*4+r (m); f16 stores
    #pragma unroll
    for (int tn = 0; tn < 4; ++tn) {
        int n = bn + wc * 64 + tn * 16 + jl;
        float bias = b0[n] + b1[n];
        #pragma unroll
        for (int tm = 0; tm < 4; ++tm) {
            int m = bm + wr * 64 + tm * 16 + rg * 4;
            #pragma unroll
            for (int r = 0; r < 4; ++r)
                C[(size_t)(m + r) * G4 + n] = (_Float16)(acc[tm][tn][r] + bias);
        }
    }
}

// ---------------- LSTM scan v16: v15 + split-kc accumulators ----------------
// 128 blocks = 2dir x 64batch, 512 thr (8 waves). Identical math to v15
// (R19/R20-proven 246 us) except each cc accumulator chain is split in two:
// accA over kc{0,1} (init = pre), accB over kc{2,3} (init = 0); row-0 scalars
// added in the tail. 8 independent 2-deep MFMA chains pipeline fully, cutting
// ~2 MFMA dep-latencies (~70 cyc) of exposed completion time per step.
__global__ __launch_bounds__(512) void lstm_scan_v16(
    const _Float16* __restrict__ pre_f, const _Float16* __restrict__ pre_b,
    const float* __restrict__ whh_f, const float* __restrict__ whh_b,
    _Float16* __restrict__ out)
{
    const int dir = blockIdx.x >> 6;
    const int b   = blockIdx.x & 63;
    const _Float16* __restrict__ pre = dir ? pre_b : pre_f;
    const float* __restrict__ w_hh   = dir ? whh_b : whh_f;

    const int tid = threadIdx.x;
    const int w   = tid >> 6;        // wave 0..7
    const int l   = tid & 63;
    const int jl  = l & 15;
    const int rg  = l >> 4;          // 0..3

    __shared__ _Float16 h_lds[2][HH];

    // B fragments: gate rows (cc*128 + w*16 + jl), k = kc*32 + rg*8 + e
    f16x8v bw[4][4];
    #pragma unroll
    for (int cc = 0; cc < 4; ++cc) {
        const float* wr_ = w_hh + (size_t)(cc * HH + w * 16 + jl) * HH + rg * 8;
        #pragma unroll
        for (int kc = 0; kc < 4; ++kc) {
            const float* p_ = wr_ + kc * 32;
            f16x8v f;
            #pragma unroll
            for (int e = 0; e < 8; ++e) f[e] = (_Float16)p_[e];
            bw[cc][kc] = f;
        }
    }

    if (tid < 2 * HH) ((_Float16*)h_lds)[tid] = (_Float16)0.f;

    // pre ring (f16 loads): only lanes 0-15 consumed
    const size_t base = (size_t)b * TT * G4 + w * 16 + jl;
    float pf[PF][4];
    #pragma unroll
    for (int u = 0; u < PF; ++u) {
        int tau = dir ? (TT - 1 - u) : u;
        #pragma unroll
        for (int cc = 0; cc < 4; ++cc)
            pf[u][cc] = (float)pre[base + (size_t)tau * G4 + cc * HH];
    }

    float c = 0.f;
    const float ASIG = -1.4426950408889634f;  // -log2(e)
    const float ATAN =  2.8853900817779268f;  // 2*log2(e)

    __syncthreads();

    for (int s0 = 0; s0 < TT; s0 += PF) {
        #pragma unroll
        for (int u = 0; u < PF; ++u) {
            const int s = s0 + u;
            const int cur = u & 1;            // parity(s) == parity(u)

            // A fragments: wave-uniform per rg-group
            f16x8v a[4];
            #pragma unroll
            for (int kc = 0; kc < 4; ++kc)
                a[kc] = *(const f16x8v*)&h_lds[cur][kc * 32 + rg * 8];

            // split accumulators: accA(kc0,1) init=pre, accB(kc2,3) init=0
            f32x4 accA[4], accB[4];
            #pragma unroll
            for (int cc = 0; cc < 4; ++cc) {
                accA[cc] = (f32x4){pf[u][cc], 0.f, 0.f, 0.f};
                accB[cc] = (f32x4){0.f, 0.f, 0.f, 0.f};
            }

            // ring refill (clamped; loads survive across lgkm-only barriers)
            {
                int sn = s + PF;
                int taun = dir ? (TT - 1 - sn) : sn;
                taun = taun < 0 ? 0 : (taun > TT - 1 ? TT - 1 : taun);
                #pragma unroll
                for (int cc = 0; cc < 4; ++cc)
                    pf[u][cc] = (float)pre[base + (size_t)taun * G4 + cc * HH];
            }

            // 16 MFMA: 8 independent 2-deep chains
            #pragma unroll
            for (int cc = 0; cc < 4; ++cc) {
                accA[cc] = __builtin_amdgcn_mfma_f32_16x16x32_f16(a[0], bw[cc][0], accA[cc], 0, 0, 0);
                accB[cc] = __builtin_amdgcn_mfma_f32_16x16x32_f16(a[2], bw[cc][2], accB[cc], 0, 0, 0);
            }
            #pragma unroll
            for (int cc = 0; cc < 4; ++cc) {
                accA[cc] = __builtin_amdgcn_mfma_f32_16x16x32_f16(a[1], bw[cc][1], accA[cc], 0, 0, 0);
                accB[cc] = __builtin_amdgcn_mfma_f32_16x16x32_f16(a[3], bw[cc][3], accB[cc], 0, 0, 0);
            }

            // tail: lanes 0-15 hold cell (w*16+l): i,f,g,o in accA+accB [0]
            if (l < 16) {
                float gi = accA[0][0] + accB[0][0];
                float gf = accA[1][0] + accB[1][0];
                float gg = accA[2][0] + accB[2][0];
                float go = accA[3][0] + accB[3][0];
                float ei = __builtin_amdgcn_exp2f(ASIG * gi);
                float si = __builtin_amdgcn_rcpf(1.f + ei);
                float ef = __builtin_amdgcn_exp2f(ASIG * gf);
                float sf = __builtin_amdgcn_rcpf(1.f + ef);
                float eg = __builtin_amdgcn_exp2f(ATAN * gg);
                float tg = 1.f - 2.f * __builtin_amdgcn_rcpf(1.f + eg);
                float eo = __builtin_amdgcn_exp2f(ASIG * go);
                float so = __builtin_amdgcn_rcpf(1.f + eo);
                c = fmaf(sf, c, si * tg);
                float e2 = __builtin_amdgcn_exp2f(ATAN * c);
                float hval = so * (1.f - 2.f * __builtin_amdgcn_rcpf(1.f + e2));
                int j = w * 16 + l;
                _Float16 h16 = (_Float16)hval;
                h_lds[cur ^ 1][j] = h16;
                int tau = dir ? (TT - 1 - s) : s;
                out[((size_t)b * TT + tau) * (2 * HH) + dir * HH + j] = h16;
            }
            barrier_lds_only();
        }
    }
}

// ---------------- FC v3: h2 f16, w_fc staged in LDS (R19-proven) ----------------
__global__ __launch_bounds__(256) void fc_v3(
    const _Float16* __restrict__ h2, const float* __restrict__ w_fc,
    const float* __restrict__ b_fc, float* __restrict__ out)
{
    __shared__ float4 wsT[64][64];          // [k4][n]
    const int tid = threadIdx.x;
    const int bm  = blockIdx.x * 64;
    const int n   = tid & 63;
    const int mg  = tid >> 6;

    #pragma unroll
    for (int qq = 0; qq < 16; ++qq) {
        int id = qq * 256 + tid;
        int nn = id >> 6, k4 = id & 63;
        wsT[k4][nn] = *(const float4*)&w_fc[(size_t)nn * 256 + k4 * 4];
    }
    __syncthreads();

    const float bias = b_fc[n];
    const _Float16* hrow = h2 + (size_t)(bm + mg * 16) * 256;

    float acc[16];
    #pragma unroll
    for (int mi = 0; mi < 16; ++mi) acc[mi] = 0.f;

    #pragma unroll 2
    for (int k4 = 0; k4 < 64; ++k4) {
        float4 w4 = wsT[k4][n];
        #pragma unroll
        for (int mi = 0; mi < 16; ++mi) {
            f16x4v hv = *(const f16x4v*)(hrow + (size_t)mi * 256 + k4 * 4);
            acc[mi] = fmaf((float)hv[0], w4.x, acc[mi]);
            acc[mi] = fmaf((float)hv[1], w4.y, acc[mi]);
            acc[mi] = fmaf((float)hv[2], w4.z, acc[mi]);
            acc[mi] = fmaf((float)hv[3], w4.w, acc[mi]);
        }
    }
    #pragma unroll
    for (int mi = 0; mi < 16; ++mi)
        out[(size_t)(bm + mg * 16 + mi) * 64 + n] = acc[mi] + bias;
}

extern "C" void kernel_launch(void* const* d_in, const int* in_sizes, int n_in,
                              void* d_out, int out_size, void* d_ws, size_t ws_size,
                              hipStream_t stream) {
    const float* x        = (const float*)d_in[0];
    const float* w_ih_l0  = (const float*)d_in[1];
    const float* w_hh_l0  = (const float*)d_in[2];
    const float* b_ih_l0  = (const float*)d_in[3];
    const float* b_hh_l0  = (const float*)d_in[4];
    const float* w_ih_l0r = (const float*)d_in[5];
    const float* w_hh_l0r = (const float*)d_in[6];
    const float* b_ih_l0r = (const float*)d_in[7];
    const float* b_hh_l0r = (const float*)d_in[8];
    const float* w_ih_l1  = (const float*)d_in[9];
    const float* w_hh_l1  = (const float*)d_in[10];
    const float* b_ih_l1  = (const float*)d_in[11];
    const float* b_hh_l1  = (const float*)d_in[12];
    const float* w_ih_l1r = (const float*)d_in[13];
    const float* w_hh_l1r = (const float*)d_in[14];
    const float* b_ih_l1r = (const float*)d_in[15];
    const float* b_hh_l1r = (const float*)d_in[16];
    const float* w_fc     = (const float*)d_in[17];
    const float* b_fc     = (const float*)d_in[18];

    // all-f16 scratch layout in d_ws (~105 MB total)
    _Float16* wsh    = (_Float16*)d_ws;
    _Float16* preh_f = wsh;                      // 16,777,216 f16
    _Float16* preh_b = preh_f + 16777216;        // 16,777,216
    _Float16* out0h  = preh_b + 16777216;        //  8,388,608
    _Float16* out1h  = out0h  + 8388608;         //  8,388,608
    _Float16* xf16   = out1h  + 8388608;         //  2,097,152
    _Float16* w0f    = xf16   + 2097152;         //     32,768
    _Float16* w0r    = w0f    + 32768;
    _Float16* w1f    = w0r    + 32768;           //    131,072
    _Float16* w1r    = w1f    + 131072;

    dim3 gg(256, 4, 2);  // M/128 x 512/128 x {fwd,bwd}

    // all converts in ONE launch (inputs const -> up front)
    convert_all<<<1024, 256, 0, stream>>>(
        (const float4*)x,         (f16x4v*)xf16, 524288,
        (const float4*)w_ih_l0,   (f16x4v*)w0f,  8192,
        (const float4*)w_ih_l0r,  (f16x4v*)w0r,  8192,
        (const float4*)w_ih_l1,   (f16x4v*)w1f,  32768,
        (const float4*)w_ih_l1r,  (f16x4v*)w1r,  32768);

    // Layer 0: fwd+bwd gemm in one launch
    gemm_f16z<64><<<gg, 256, 0, stream>>>(xf16, w0f, w0r,
        b_ih_l0, b_hh_l0, b_ih_l0r, b_hh_l0r, preh_f, preh_b);
    lstm_scan_v16<<<128, 512, 0, stream>>>(preh_f, preh_b, w_hh_l0, w_hh_l0r, out0h);

    // Layer 1
    gemm_f16z<256><<<gg, 256, 0, stream>>>(out0h, w1f, w1r,
        b_ih_l1, b_hh_l1, b_ih_l1r, b_hh_l1r, preh_f, preh_b);
    lstm_scan_v16<<<128, 512, 0, stream>>>(preh_f, preh_b, w_hh_l1, w_hh_l1r, out1h);

    // FC
    fc_v3<<<512, 256, 0, stream>>>(out1h, w_fc, b_fc, (float*)d_out);
}

// Round 22
// 552.401 us; speedup vs baseline: 1.0728x; 1.0728x over previous
//
#include <hip/hip_runtime.h>

#define TT 512   // sequence length
#define BB 64    // batch
#define HH 128   // hidden
#define G4 512   // 4*H
#define PF 4     // prefetch ring depth (even, divides TT)

typedef float f32x4  __attribute__((ext_vector_type(4)));
typedef _Float16 f16x4v __attribute__((ext_vector_type(4)));
typedef _Float16 f16x8v __attribute__((ext_vector_type(8)));

// barrier that waits ONLY on LDS (lgkmcnt) -- global loads/stores stay in flight
__device__ __forceinline__ void barrier_lds_only() {
    asm volatile("s_waitcnt lgkmcnt(0)\n\ts_barrier" ::: "memory");
}

// ---------------- merged fp32 -> fp16 convert: 5 segments, 1 launch ----------------
__global__ __launch_bounds__(256) void convert_all(
    const float4* __restrict__ s0, f16x4v* __restrict__ d0, int n0,
    const float4* __restrict__ s1, f16x4v* __restrict__ d1, int n1,
    const float4* __restrict__ s2, f16x4v* __restrict__ d2, int n2,
    const float4* __restrict__ s3, f16x4v* __restrict__ d3, int n3,
    const float4* __restrict__ s4, f16x4v* __restrict__ d4, int n4)
{
    const int tid0 = blockIdx.x * 256 + threadIdx.x;
    const int strd = gridDim.x * 256;
    #define CVT(S, D, N)                                            \
        for (int i = tid0; i < (N); i += strd) {                    \
            float4 f = (S)[i];                                      \
            f16x4v h;                                               \
            h[0] = (_Float16)f.x; h[1] = (_Float16)f.y;             \
            h[2] = (_Float16)f.z; h[3] = (_Float16)f.w;             \
            (D)[i] = h;                                             \
        }
    CVT(s0, d0, n0)
    CVT(s1, d1, n1)
    CVT(s2, d2, n2)
    CVT(s3, d3, n3)
    CVT(s4, d4, n4)
    #undef CVT
}

// ---------------- f16 pre-GEMM, fwd+bwd fused via blockIdx.z (R20-proven) ----------
template<int K>
__global__ __launch_bounds__(256) void gemm_f16z(
    const _Float16* __restrict__ Af,
    const _Float16* __restrict__ Wf0, const _Float16* __restrict__ Wf1,
    const float* __restrict__ b0f, const float* __restrict__ b1f,
    const float* __restrict__ b0r, const float* __restrict__ b1r,
    _Float16* __restrict__ C0, _Float16* __restrict__ C1)
{
    const int z = blockIdx.z;
    const _Float16* __restrict__ Wf = z ? Wf1 : Wf0;
    const float* __restrict__ b0 = z ? b0r : b0f;
    const float* __restrict__ b1 = z ? b1r : b1f;
    _Float16* __restrict__ C = z ? C1 : C0;

    constexpr int NC  = K / 32;
    constexpr int LDA = 40;                  // f16 per staged row (32 + 8 pad)
    __shared__ _Float16 As[128 * LDA];
    __shared__ _Float16 Ws[128 * LDA];

    const int bm  = blockIdx.x * 128;
    const int bn  = blockIdx.y * 128;
    const int tid = threadIdx.x;
    const int wv  = tid >> 6;
    const int l   = tid & 63;
    const int jl  = l & 15;
    const int rg  = l >> 4;
    const int wr  = wv >> 1;
    const int wc  = wv & 1;

    const int sr = tid >> 1;
    const int sc = (tid & 1) * 16;

    const _Float16* Ap = Af + (size_t)(bm + sr) * K + sc;
    const _Float16* Wp = Wf + (size_t)(bn + sr) * K + sc;

    f32x4 acc[4][4];
    #pragma unroll
    for (int i = 0; i < 4; ++i)
        #pragma unroll
        for (int j = 0; j < 4; ++j)
            acc[i][j] = (f32x4){0.f, 0.f, 0.f, 0.f};

    f16x8v pa[2], pw[2];
    pa[0] = *(const f16x8v*)(Ap);     pa[1] = *(const f16x8v*)(Ap + 8);
    pw[0] = *(const f16x8v*)(Wp);     pw[1] = *(const f16x8v*)(Wp + 8);

    #pragma unroll 1
    for (int c = 0; c < NC; ++c) {
        __syncthreads();
        {
            int off = sr * LDA + sc;
            *(f16x8v*)&As[off]     = pa[0];
            *(f16x8v*)&As[off + 8] = pa[1];
            *(f16x8v*)&Ws[off]     = pw[0];
            *(f16x8v*)&Ws[off + 8] = pw[1];
        }
        __syncthreads();
        if (c + 1 < NC) {
            pa[0] = *(const f16x8v*)(Ap + (c + 1) * 32);
            pa[1] = *(const f16x8v*)(Ap + (c + 1) * 32 + 8);
            pw[0] = *(const f16x8v*)(Wp + (c + 1) * 32);
            pw[1] = *(const f16x8v*)(Wp + (c + 1) * 32 + 8);
        }
        f16x8v ah[4], wh[4];
        #pragma unroll
        for (int t = 0; t < 4; ++t) {
            ah[t] = *(const f16x8v*)&As[(wr * 64 + t * 16 + jl) * LDA + rg * 8];
            wh[t] = *(const f16x8v*)&Ws[(wc * 64 + t * 16 + jl) * LDA + rg * 8];
        }
        #pragma unroll
        for (int tm = 0; tm < 4; ++tm)
            #pragma unroll
            for (int tn = 0; tn < 4; ++tn)
                acc[tm][tn] = __builtin_amdgcn_mfma_f32_16x16x32_f16(
                    ah[tm], wh[tn], acc[tm][tn], 0, 0, 0);
    }

    // epilogue: C layout col=lane&15 (n), row=(lane>>4)*4+r (m); f16 stores
    #pragma unroll
    for (int tn = 0; tn < 4; ++tn) {
        int n = bn + wc * 64 + tn * 16 + jl;
        float bias = b0[n] + b1[n];
        #pragma unroll
        for (int tm = 0; tm < 4; ++tm) {
            int m = bm + wr * 64 + tm * 16 + rg * 4;
            #pragma unroll
            for (int r = 0; r < 4; ++r)
                C[(size_t)(m + r) * G4 + n] = (_Float16)(acc[tm][tn][r] + bias);
        }
    }
}

// ---------------- LSTM scan v15 (R19/R20-proven: 246 us, absmax 9.77e-4) ----------
__global__ __launch_bounds__(512) void lstm_scan_v15(
    const _Float16* __restrict__ pre_f, const _Float16* __restrict__ pre_b,
    const float* __restrict__ whh_f, const float* __restrict__ whh_b,
    _Float16* __restrict__ out)
{
    const int dir = blockIdx.x >> 6;
    const int b   = blockIdx.x & 63;
    const _Float16* __restrict__ pre = dir ? pre_b : pre_f;
    const float* __restrict__ w_hh   = dir ? whh_b : whh_f;

    const int tid = threadIdx.x;
    const int w   = tid >> 6;        // wave 0..7
    const int l   = tid & 63;
    const int jl  = l & 15;
    const int rg  = l >> 4;          // 0..3

    __shared__ _Float16 h_lds[2][HH];

    // B fragments: gate rows (cc*128 + w*16 + jl), k = kc*32 + rg*8 + e
    f16x8v bw[4][4];
    #pragma unroll
    for (int cc = 0; cc < 4; ++cc) {
        const float* wr_ = w_hh + (size_t)(cc * HH + w * 16 + jl) * HH + rg * 8;
        #pragma unroll
        for (int kc = 0; kc < 4; ++kc) {
            const float* p_ = wr_ + kc * 32;
            f16x8v f;
            #pragma unroll
            for (int e = 0; e < 8; ++e) f[e] = (_Float16)p_[e];
            bw[cc][kc] = f;
        }
    }

    if (tid < 2 * HH) ((_Float16*)h_lds)[tid] = (_Float16)0.f;

    // pre ring (f16 loads): only lanes 0-15 consumed
    const size_t base = (size_t)b * TT * G4 + w * 16 + jl;
    float pf[PF][4];
    #pragma unroll
    for (int u = 0; u < PF; ++u) {
        int tau = dir ? (TT - 1 - u) : u;
        #pragma unroll
        for (int cc = 0; cc < 4; ++cc)
            pf[u][cc] = (float)pre[base + (size_t)tau * G4 + cc * HH];
    }

    float c = 0.f;
    const float ASIG = -1.4426950408889634f;  // -log2(e)
    const float ATAN =  2.8853900817779268f;  // 2*log2(e)

    __syncthreads();

    for (int s0 = 0; s0 < TT; s0 += PF) {
        #pragma unroll
        for (int u = 0; u < PF; ++u) {
            const int s = s0 + u;
            const int cur = u & 1;            // parity(s) == parity(u)

            // A fragments: wave-uniform per rg-group
            f16x8v a[4];
            #pragma unroll
            for (int kc = 0; kc < 4; ++kc)
                a[kc] = *(const f16x8v*)&h_lds[cur][kc * 32 + rg * 8];

            // C init from pre (row 0 real), pv captured BEFORE refill
            f32x4 acc[4];
            #pragma unroll
            for (int cc = 0; cc < 4; ++cc)
                acc[cc] = (f32x4){pf[u][cc], 0.f, 0.f, 0.f};

            // ring refill (clamped; loads survive across lgkm-only barriers)
            {
                int sn = s + PF;
                int taun = dir ? (TT - 1 - sn) : sn;
                taun = taun < 0 ? 0 : (taun > TT - 1 ? TT - 1 : taun);
                #pragma unroll
                for (int cc = 0; cc < 4; ++cc)
                    pf[u][cc] = (float)pre[base + (size_t)taun * G4 + cc * HH];
            }

            // 16 MFMA: G[gates of this wave] += Whh-chunk . h-chunk
            #pragma unroll
            for (int cc = 0; cc < 4; ++cc)
                #pragma unroll
                for (int kc = 0; kc < 4; ++kc)
                    acc[cc] = __builtin_amdgcn_mfma_f32_16x16x32_f16(
                        a[kc], bw[cc][kc], acc[cc], 0, 0, 0);

            // tail: lanes 0-15 hold cell (w*16+l): i,f,g,o in acc[cc][0]
            if (l < 16) {
                float gi = acc[0][0], gf = acc[1][0], gg = acc[2][0], go = acc[3][0];
                float ei = __builtin_amdgcn_exp2f(ASIG * gi);
                float si = __builtin_amdgcn_rcpf(1.f + ei);
                float ef = __builtin_amdgcn_exp2f(ASIG * gf);
                float sf = __builtin_amdgcn_rcpf(1.f + ef);
                float eg = __builtin_amdgcn_exp2f(ATAN * gg);
                float tg = 1.f - 2.f * __builtin_amdgcn_rcpf(1.f + eg);
                float eo = __builtin_amdgcn_exp2f(ASIG * go);
                float so = __builtin_amdgcn_rcpf(1.f + eo);
                c = fmaf(sf, c, si * tg);
                float e2 = __builtin_amdgcn_exp2f(ATAN * c);
                float hval = so * (1.f - 2.f * __builtin_amdgcn_rcpf(1.f + e2));
                int j = w * 16 + l;
                _Float16 h16 = (_Float16)hval;
                h_lds[cur ^ 1][j] = h16;
                int tau = dir ? (TT - 1 - s) : s;
                out[((size_t)b * TT + tau) * (2 * HH) + dir * HH + j] = h16;
            }
            barrier_lds_only();
        }
    }
}

// ---------------- FC v3: h2 f16, w_fc staged in LDS (R19-proven) ----------------
__global__ __launch_bounds__(256) void fc_v3(
    const _Float16* __restrict__ h2, const float* __restrict__ w_fc,
    const float* __restrict__ b_fc, float* __restrict__ out)
{
    __shared__ float4 wsT[64][64];          // [k4][n]
    const int tid = threadIdx.x;
    const int bm  = blockIdx.x * 64;
    const int n   = tid & 63;
    const int mg  = tid >> 6;

    #pragma unroll
    for (int qq = 0; qq < 16; ++qq) {
        int id = qq * 256 + tid;
        int nn = id >> 6, k4 = id & 63;
        wsT[k4][nn] = *(const float4*)&w_fc[(size_t)nn * 256 + k4 * 4];
    }
    __syncthreads();

    const float bias = b_fc[n];
    const _Float16* hrow = h2 + (size_t)(bm + mg * 16) * 256;

    float acc[16];
    #pragma unroll
    for (int mi = 0; mi < 16; ++mi) acc[mi] = 0.f;

    #pragma unroll 2
    for (int k4 = 0; k4 < 64; ++k4) {
        float4 w4 = wsT[k4][n];
        #pragma unroll
        for (int mi = 0; mi < 16; ++mi) {
            f16x4v hv = *(const f16x4v*)(hrow + (size_t)mi * 256 + k4 * 4);
            acc[mi] = fmaf((float)hv[0], w4.x, acc[mi]);
            acc[mi] = fmaf((float)hv[1], w4.y, acc[mi]);
            acc[mi] = fmaf((float)hv[2], w4.z, acc[mi]);
            acc[mi] = fmaf((float)hv[3], w4.w, acc[mi]);
        }
    }
    #pragma unroll
    for (int mi = 0; mi < 16; ++mi)
        out[(size_t)(bm + mg * 16 + mi) * 64 + n] = acc[mi] + bias;
}

extern "C" void kernel_launch(void* const* d_in, const int* in_sizes, int n_in,
                              void* d_out, int out_size, void* d_ws, size_t ws_size,
                              hipStream_t stream) {
    const float* x        = (const float*)d_in[0];
    const float* w_ih_l0  = (const float*)d_in[1];
    const float* w_hh_l0  = (const float*)d_in[2];
    const float* b_ih_l0  = (const float*)d_in[3];
    const float* b_hh_l0  = (const float*)d_in[4];
    const float* w_ih_l0r = (const float*)d_in[5];
    const float* w_hh_l0r = (const float*)d_in[6];
    const float* b_ih_l0r = (const float*)d_in[7];
    const float* b_hh_l0r = (const float*)d_in[8];
    const float* w_ih_l1  = (const float*)d_in[9];
    const float* w_hh_l1  = (const float*)d_in[10];
    const float* b_ih_l1  = (const float*)d_in[11];
    const float* b_hh_l1  = (const float*)d_in[12];
    const float* w_ih_l1r = (const float*)d_in[13];
    const float* w_hh_l1r = (const float*)d_in[14];
    const float* b_ih_l1r = (const float*)d_in[15];
    const float* b_hh_l1r = (const float*)d_in[16];
    const float* w_fc     = (const float*)d_in[17];
    const float* b_fc     = (const float*)d_in[18];

    // all-f16 scratch layout in d_ws (~105 MB total)
    _Float16* wsh    = (_Float16*)d_ws;
    _Float16* preh_f = wsh;                      // 16,777,216 f16
    _Float16* preh_b = preh_f + 16777216;        // 16,777,216
    _Float16* out0h  = preh_b + 16777216;        //  8,388,608
    _Float16* out1h  = out0h  + 8388608;         //  8,388,608
    _Float16* xf16   = out1h  + 8388608;         //  2,097,152
    _Float16* w0f    = xf16   + 2097152;         //     32,768
    _Float16* w0r    = w0f    + 32768;
    _Float16* w1f    = w0r    + 32768;           //    131,072
    _Float16* w1r    = w1f    + 131072;

    dim3 gg(256, 4, 2);  // M/128 x 512/128 x {fwd,bwd}

    // all converts in ONE launch (inputs const -> up front)
    convert_all<<<1024, 256, 0, stream>>>(
        (const float4*)x,         (f16x4v*)xf16, 524288,
        (const float4*)w_ih_l0,   (f16x4v*)w0f,  8192,
        (const float4*)w_ih_l0r,  (f16x4v*)w0r,  8192,
        (const float4*)w_ih_l1,   (f16x4v*)w1f,  32768,
        (const float4*)w_ih_l1r,  (f16x4v*)w1r,  32768);

    // Layer 0: fwd+bwd gemm in one launch
    gemm_f16z<64><<<gg, 256, 0, stream>>>(xf16, w0f, w0r,
        b_ih_l0, b_hh_l0, b_ih_l0r, b_hh_l0r, preh_f, preh_b);
    lstm_scan_v15<<<128, 512, 0, stream>>>(preh_f, preh_b, w_hh_l0, w_hh_l0r, out0h);

    // Layer 1
    gemm_f16z<256><<<gg, 256, 0, stream>>>(out0h, w1f, w1r,
        b_ih_l1, b_hh_l1, b_ih_l1r, b_hh_l1r, preh_f, preh_b);
    lstm_scan_v15<<<128, 512, 0, stream>>>(preh_f, preh_b, w_hh_l1, w_hh_l1r, out1h);

    // FC
    fc_v3<<<512, 256, 0, stream>>>(out1h, w_fc, b_fc, (float*)d_out);
}